// Round 1
// baseline (153.155 us; speedup 1.0000x reference)
//
#include <hip/hip_runtime.h>
#include <stdint.h>

#define DEVFN __device__ __forceinline__

// ---------- strict f32 ops (no FMA contraction, matches XLA strict mode) ----------
DEVFN float mulf(float a, float b) {
#pragma clang fp contract(off)
  return a * b;
}
DEVFN float addf(float a, float b) {
#pragma clang fp contract(off)
  return a + b;
}
DEVFN float subf(float a, float b) {
#pragma clang fp contract(off)
  return a - b;
}

// ---------- threefry2x32 (JAX), partitionable counter scheme ----------
// One 32-bit draw for counter (hi=0, lo=ctr): returns y0 ^ y1.
DEVFN uint32_t tf_bits32(uint32_t k0, uint32_t k1, uint32_t ctr) {
  uint32_t ks2 = k0 ^ k1 ^ 0x1BD11BDAu;
  uint32_t x0 = k0;        // 0 + ks[0]
  uint32_t x1 = ctr + k1;  // ctr + ks[1]
#define TFR(d) { x0 += x1; x1 = (x1 << (d)) | (x1 >> (32 - (d))); x1 ^= x0; }
  TFR(13) TFR(15) TFR(26) TFR(6)
  x0 += k1; x1 += ks2 + 1u;
  TFR(17) TFR(29) TFR(16) TFR(24)
  x0 += ks2; x1 += k0 + 2u;
  TFR(13) TFR(15) TFR(26) TFR(6)
  x0 += k0; x1 += k1 + 3u;
  TFR(17) TFR(29) TFR(16) TFR(24)
  x0 += k1; x1 += ks2 + 4u;
  TFR(13) TFR(15) TFR(26) TFR(6)
  x0 += ks2; x1 += k0 + 5u;
#undef TFR
  return x0 ^ x1;
}

// ---------- XLA-CPU Cephes log (llvm_ir_runtime GenerateVF32Log / Eigen plog), unfused ----------
DEVFN float xla_cephes_logf(float in) {
  float xv = fmaxf(in, __uint_as_float(0x00800000u));  // min normal pos
  uint32_t bits = __float_as_uint(xv);
  int ei = (int)(bits >> 23) - 126;
  float m = __uint_as_float((bits & 0x007FFFFFu) | 0x3F000000u);  // [0.5,1)
  float e = (float)ei;
  const float SQRTHF = __uint_as_float(0x3F3504F3u);  // 0.70710678f
  bool lt = m < SQRTHF;
  float tmp = lt ? m : 0.0f;
  m = subf(m, 1.0f);
  e = subf(e, lt ? 1.0f : 0.0f);
  m = addf(m, tmp);
  float z = mulf(m, m);
  float y = 7.0376836292E-2f;
  y = addf(mulf(y, m), -1.1514610310E-1f);
  y = addf(mulf(y, m),  1.1676998740E-1f);
  y = addf(mulf(y, m), -1.2420140846E-1f);
  y = addf(mulf(y, m),  1.4249322787E-1f);
  y = addf(mulf(y, m), -1.6668057665E-1f);
  y = addf(mulf(y, m),  2.0000714765E-1f);
  y = addf(mulf(y, m), -2.4999993993E-1f);
  y = addf(mulf(y, m),  3.3333331174E-1f);
  y = mulf(y, m);
  y = mulf(y, z);                       // x^3 * P(x)
  y = addf(y, mulf(e, -2.12194440e-4f));
  y = subf(y, mulf(z, 0.5f));
  m = addf(m, y);
  m = addf(m, mulf(e, 0.693359375f));
  return m;
}

// ---------- XLA ElementalIrEmitter::EmitLog1p ----------
DEVFN float xla_log1pf(float a) {
  float large = xla_cephes_logf(addf(a, 1.0f));
  float small = mulf(addf(mulf(-0.5f, a), 1.0f), a);
  return (fabsf(a) < __uint_as_float(0x38D1B717u)) ? small : large;  // 1e-4
}

// ---------- XLA chlo ErfInv32 (Giles polynomial), unfused ----------
DEVFN float xla_erfinvf(float u) {
  float nxx = -mulf(u, u);
  float w = -xla_log1pf(nxx);
  float p;
  if (w < 5.0f) {
    float s = subf(w, 2.5f);
    p = 2.81022636e-08f;
    p = addf(mulf(p, s), 3.43273939e-07f);
    p = addf(mulf(p, s), -3.5233877e-06f);
    p = addf(mulf(p, s), -4.39150654e-06f);
    p = addf(mulf(p, s), 0.00021858087f);
    p = addf(mulf(p, s), -0.00125372503f);
    p = addf(mulf(p, s), -0.00417768164f);
    p = addf(mulf(p, s), 0.246640727f);
    p = addf(mulf(p, s), 1.50140941f);
  } else {
    float s = subf(__fsqrt_rn(w), 3.0f);
    p = -0.000200214257f;
    p = addf(mulf(p, s), 0.000100950558f);
    p = addf(mulf(p, s), 0.00134934322f);
    p = addf(mulf(p, s), -0.00367342844f);
    p = addf(mulf(p, s), 0.00573950773f);
    p = addf(mulf(p, s), -0.0076224613f);
    p = addf(mulf(p, s), 0.00943887047f);
    p = addf(mulf(p, s), 1.00167406f);
    p = addf(mulf(p, s), 2.83297682f);
  }
  return mulf(p, u);
}

// bits -> [0,1) float exactly as jax.random.uniform
DEVFN float unitf(uint32_t bits) {
  return subf(__uint_as_float((bits >> 9) | 0x3F800000u), 1.0f);
}

// jax.random.normal element from raw bits
DEVFN float jax_normal(uint32_t bits) {
  float f = unitf(bits);
  const float lo = __uint_as_float(0xBF7FFFFFu);  // nextafter(-1,0)
  // u = max(lo, f*(1-lo) + lo); (1-lo) rounds to 2.0f in f32 (tie-to-even)
  float u = fmaxf(lo, addf(mulf(f, 2.0f), lo));
  const float sqrt2 = __uint_as_float(0x3FB504F3u);
  return mulf(sqrt2, xla_erfinvf(u));
}

struct PMKeys {
  uint32_t ki0, ki1;       // k_init
  uint32_t sk[5][4][2];    // sample key per (iter t, search step s)
};

// ---------- Kernel A: D[b][y][x] = sum_{py,px,c} (S-T)^2, exact linear order ----------
__global__ __launch_bounds__(256) void compute_d(const float* __restrict__ S,
                                                 const float* __restrict__ T,
                                                 float* __restrict__ D) {
  const int x = threadIdx.x;
  const int y = blockIdx.x & 255;
  const int b = blockIdx.x >> 8;
  const int chs = 65536;  // 256*256
  const float* Sb = S + (size_t)b * 32 * chs;
  const float* Tb = T + (size_t)b * 32 * chs;
  float acc = 0.0f;
  for (int py = 0; py < 3; ++py) {
    int yy = y + py - 1;
    if (yy < 0 || yy > 255) continue;  // zero-pad terms add exact +0.0
    for (int px = 0; px < 3; ++px) {
      int xx = x + px - 1;
      if (xx < 0 || xx > 255) continue;
      int off = yy * 256 + xx;
      for (int c = 0; c < 32; ++c) {
        float d = subf(Sb[c * chs + off], Tb[c * chs + off]);
        acc = addf(acc, mulf(d, d));
      }
    }
  }
  D[b * chs + y * 256 + x] = acc;
}

// ---------- Kernel B: full PatchMatch, one block per (b,row) ----------
__global__ __launch_bounds__(256) void pm_kernel(const float* __restrict__ D,
                                                 float* __restrict__ out,
                                                 PMKeys K) {
  const int j = threadIdx.x;
  const int bb = blockIdx.x >> 8;
  const int i = blockIdx.x & 255;
  const float* Db = D + bb * 65536;
  __shared__ float sy[256], sx[256];

  const uint32_t idx_y = (uint32_t)(bb * 131072 + i * 256 + j);
  const uint32_t idx_x = idx_y + 65536u;

  // init: uniform * 255
  float y = mulf(unitf(tf_bits32(K.ki0, K.ki1, idx_y)), 255.0f);
  float x = mulf(unitf(tf_bits32(K.ki0, K.ki1, idx_x)), 255.0f);

  auto lookup = [&](float yy, float xx) -> float {
    int iy = (int)rintf(yy);  // jnp.round = half-to-even = rintf
    int ix = (int)rintf(xx);
    iy = min(max(iy, 0), 255);
    ix = min(max(ix, 0), 255);
    return Db[iy * 256 + ix];
  };

  for (int t = 0; t < 5; ++t) {
    // propagate direction=+1: shifted[j] = nnf[j-1]
    sy[j] = y; sx[j] = x;
    __syncthreads();
    {
      int jn = (j + 255) & 255;
      float yn = sy[jn], xn = sx[jn];
      float cur = lookup(y, x);
      float shf = lookup(yn, xn);
      if (shf < cur) { y = yn; x = xn; }
    }
    __syncthreads();
    // propagate direction=-1: shifted[j] = nnf[j+1]
    sy[j] = y; sx[j] = x;
    __syncthreads();
    {
      int jn = (j + 1) & 255;
      float yn = sy[jn], xn = sx[jn];
      float cur = lookup(y, x);
      float shf = lookup(yn, xn);
      if (shf < cur) { y = yn; x = xn; }
    }
    __syncthreads();
    // random search
    float cur = lookup(y, x);
    float sigma = 1.0f;
    for (int s = 0; s < 4; ++s) {
      uint32_t kk0 = K.sk[t][s][0], kk1 = K.sk[t][s][1];
      float ny = jax_normal(tf_bits32(kk0, kk1, idx_y));
      float nx = jax_normal(tf_bits32(kk0, kk1, idx_x));
      float ry = fminf(fmaxf(addf(y, mulf(ny, sigma)), 0.0f), 255.0f);
      float rx = fminf(fmaxf(addf(x, mulf(nx, sigma)), 0.0f), 255.0f);
      float rd = lookup(ry, rx);
      if (rd < cur) { y = ry; x = rx; cur = rd; }
      sigma *= 0.5f;
    }
  }
  out[idx_y] = y;
  out[idx_x] = x;
}

// ---------- host-side threefry for key schedule ----------
static void h_tf(uint32_t k0, uint32_t k1, uint32_t x0, uint32_t x1,
                 uint32_t& o0, uint32_t& o1) {
  uint32_t ks2 = k0 ^ k1 ^ 0x1BD11BDAu;
  x0 += k0; x1 += k1;
#define HR(d) { x0 += x1; x1 = (x1 << (d)) | (x1 >> (32 - (d))); x1 ^= x0; }
  HR(13) HR(15) HR(26) HR(6)
  x0 += k1; x1 += ks2 + 1u;
  HR(17) HR(29) HR(16) HR(24)
  x0 += ks2; x1 += k0 + 2u;
  HR(13) HR(15) HR(26) HR(6)
  x0 += k0; x1 += k1 + 3u;
  HR(17) HR(29) HR(16) HR(24)
  x0 += k1; x1 += ks2 + 4u;
  HR(13) HR(15) HR(26) HR(6)
  x0 += ks2; x1 += k0 + 5u;
#undef HR
  o0 = x0; o1 = x1;
}

extern "C" void kernel_launch(void* const* d_in, const int* in_sizes, int n_in,
                              void* d_out, int out_size, void* d_ws, size_t ws_size,
                              hipStream_t stream) {
  const float* S = (const float*)d_in[0];
  const float* T = (const float*)d_in[1];
  float* out = (float*)d_out;
  float* D = (float*)d_ws;  // 2*256*256 floats = 512 KB

  // JAX key schedule (partitionable threefry):
  // k0 = key(1) = [0,1]; k_init, k_loop = split(k0) -> threefry(k0,(0,0)),(0,1)
  PMKeys K;
  uint32_t kl0, kl1;
  h_tf(0u, 1u, 0u, 0u, K.ki0, K.ki1);
  h_tf(0u, 1u, 0u, 1u, kl0, kl1);
  for (uint32_t t = 0; t < 5; ++t) {
    uint32_t c0, c1;
    h_tf(kl0, kl1, 0u, t, c0, c1);  // fold_in(k_loop, t)
    for (int s = 0; s < 4; ++s) {
      uint32_t n0, n1, s0, s1;
      h_tf(c0, c1, 0u, 0u, n0, n1);  // carried key
      h_tf(c0, c1, 0u, 1u, s0, s1);  // sample key
      K.sk[t][s][0] = s0; K.sk[t][s][1] = s1;
      c0 = n0; c1 = n1;
    }
  }

  hipLaunchKernelGGL(compute_d, dim3(512), dim3(256), 0, stream, S, T, D);
  hipLaunchKernelGGL(pm_kernel, dim3(512), dim3(256), 0, stream, D, out, K);
}

// Round 2
// 127.618 us; speedup vs baseline: 1.2001x; 1.2001x over previous
//
#include <hip/hip_runtime.h>
#include <stdint.h>

#define DEVFN __device__ __forceinline__

// ---------- strict f32 ops (no FMA contraction, matches XLA strict mode) ----------
DEVFN float mulf(float a, float b) {
#pragma clang fp contract(off)
  return a * b;
}
DEVFN float addf(float a, float b) {
#pragma clang fp contract(off)
  return a + b;
}
DEVFN float subf(float a, float b) {
#pragma clang fp contract(off)
  return a - b;
}

// ---------- threefry2x32 (JAX), partitionable counter scheme ----------
DEVFN uint32_t tf_bits32(uint32_t k0, uint32_t k1, uint32_t ctr) {
  uint32_t ks2 = k0 ^ k1 ^ 0x1BD11BDAu;
  uint32_t x0 = k0;        // 0 + ks[0]
  uint32_t x1 = ctr + k1;  // ctr + ks[1]
#define TFR(d) { x0 += x1; x1 = (x1 << (d)) | (x1 >> (32 - (d))); x1 ^= x0; }
  TFR(13) TFR(15) TFR(26) TFR(6)
  x0 += k1; x1 += ks2 + 1u;
  TFR(17) TFR(29) TFR(16) TFR(24)
  x0 += ks2; x1 += k0 + 2u;
  TFR(13) TFR(15) TFR(26) TFR(6)
  x0 += k0; x1 += k1 + 3u;
  TFR(17) TFR(29) TFR(16) TFR(24)
  x0 += k1; x1 += ks2 + 4u;
  TFR(13) TFR(15) TFR(26) TFR(6)
  x0 += ks2; x1 += k0 + 5u;
#undef TFR
  return x0 ^ x1;
}

// ---------- XLA-CPU Cephes log, unfused ----------
DEVFN float xla_cephes_logf(float in) {
  float xv = fmaxf(in, __uint_as_float(0x00800000u));
  uint32_t bits = __float_as_uint(xv);
  int ei = (int)(bits >> 23) - 126;
  float m = __uint_as_float((bits & 0x007FFFFFu) | 0x3F000000u);
  float e = (float)ei;
  const float SQRTHF = __uint_as_float(0x3F3504F3u);
  bool lt = m < SQRTHF;
  float tmp = lt ? m : 0.0f;
  m = subf(m, 1.0f);
  e = subf(e, lt ? 1.0f : 0.0f);
  m = addf(m, tmp);
  float z = mulf(m, m);
  float y = 7.0376836292E-2f;
  y = addf(mulf(y, m), -1.1514610310E-1f);
  y = addf(mulf(y, m),  1.1676998740E-1f);
  y = addf(mulf(y, m), -1.2420140846E-1f);
  y = addf(mulf(y, m),  1.4249322787E-1f);
  y = addf(mulf(y, m), -1.6668057665E-1f);
  y = addf(mulf(y, m),  2.0000714765E-1f);
  y = addf(mulf(y, m), -2.4999993993E-1f);
  y = addf(mulf(y, m),  3.3333331174E-1f);
  y = mulf(y, m);
  y = mulf(y, z);
  y = addf(y, mulf(e, -2.12194440e-4f));
  y = subf(y, mulf(z, 0.5f));
  m = addf(m, y);
  m = addf(m, mulf(e, 0.693359375f));
  return m;
}

DEVFN float xla_log1pf(float a) {
  float large = xla_cephes_logf(addf(a, 1.0f));
  float small = mulf(addf(mulf(-0.5f, a), 1.0f), a);
  return (fabsf(a) < __uint_as_float(0x38D1B717u)) ? small : large;
}

DEVFN float xla_erfinvf(float u) {
  float nxx = -mulf(u, u);
  float w = -xla_log1pf(nxx);
  float p;
  if (w < 5.0f) {
    float s = subf(w, 2.5f);
    p = 2.81022636e-08f;
    p = addf(mulf(p, s), 3.43273939e-07f);
    p = addf(mulf(p, s), -3.5233877e-06f);
    p = addf(mulf(p, s), -4.39150654e-06f);
    p = addf(mulf(p, s), 0.00021858087f);
    p = addf(mulf(p, s), -0.00125372503f);
    p = addf(mulf(p, s), -0.00417768164f);
    p = addf(mulf(p, s), 0.246640727f);
    p = addf(mulf(p, s), 1.50140941f);
  } else {
    float s = subf(__fsqrt_rn(w), 3.0f);
    p = -0.000200214257f;
    p = addf(mulf(p, s), 0.000100950558f);
    p = addf(mulf(p, s), 0.00134934322f);
    p = addf(mulf(p, s), -0.00367342844f);
    p = addf(mulf(p, s), 0.00573950773f);
    p = addf(mulf(p, s), -0.0076224613f);
    p = addf(mulf(p, s), 0.00943887047f);
    p = addf(mulf(p, s), 1.00167406f);
    p = addf(mulf(p, s), 2.83297682f);
  }
  return mulf(p, u);
}

DEVFN float unitf(uint32_t bits) {
  return subf(__uint_as_float((bits >> 9) | 0x3F800000u), 1.0f);
}

DEVFN float jax_normal(uint32_t bits) {
  float f = unitf(bits);
  const float lo = __uint_as_float(0xBF7FFFFFu);
  float u = fmaxf(lo, addf(mulf(f, 2.0f), lo));
  const float sqrt2 = __uint_as_float(0x3FB504F3u);
  return mulf(sqrt2, xla_erfinvf(u));
}

struct PMKeys {
  uint32_t ki0, ki1;
  uint32_t sk[5][4][2];
};
struct NK { uint32_t k[20][2]; };

// ========================================================================
// FAST PATH
// ========================================================================

// K1: Q[b][y][x][c] = (S-T)^2, channel-innermost, LDS tile transpose.
// grid 2048 (b*1024 + y*4 + quarter), block 256. Tile = 64 px x 32 c.
__global__ __launch_bounds__(256) void qdiff_kernel(const float* __restrict__ S,
                                                    const float* __restrict__ T,
                                                    float* __restrict__ Q) {
  __shared__ float lds[64 * 33];
  const int t = threadIdx.x;
  const int gid = blockIdx.x;
  const int b = gid >> 10;
  const int y = (gid >> 2) & 255;
  const int x0 = (gid & 3) << 6;
  const int xl = t & 63;
  const int cw = t >> 6;  // wave id: 4 channels per pass step
#pragma unroll
  for (int k = 0; k < 8; ++k) {
    int c = k * 4 + cw;
    size_t o = (size_t)(b * 32 + c) * 65536 + (size_t)y * 256 + x0 + xl;
    float d = subf(S[o], T[o]);
    lds[xl * 33 + c] = mulf(d, d);
  }
  __syncthreads();
  size_t base = (size_t)gid * 2048;
#pragma unroll
  for (int k = 0; k < 2; ++k) {
    int e = t * 4 + k * 1024;
    int px = e >> 5, c = e & 31;
    float4 v;
    v.x = lds[px * 33 + c];
    v.y = lds[px * 33 + c + 1];
    v.z = lds[px * 33 + c + 2];
    v.w = lds[px * 33 + c + 3];
    *(float4*)&Q[base + e] = v;
  }
}

// K2: D[b][y][x] = strict linear chain over (py, px, c) of Q runs.
__global__ __launch_bounds__(256) void dsum_kernel(const float* __restrict__ Q,
                                                   float* __restrict__ D) {
  const int x = threadIdx.x;
  const int y = blockIdx.x & 255;
  const int b = blockIdx.x >> 8;
  float acc = 0.0f;
  for (int py = 0; py < 3; ++py) {
    int yy = y + py - 1;
    if (yy < 0 || yy > 255) continue;
    for (int px = 0; px < 3; ++px) {
      int xx = x + px - 1;
      if (xx < 0 || xx > 255) continue;
      const float4* p = (const float4*)&Q[((size_t)b * 65536 + yy * 256 + xx) * 32];
      float4 v0 = p[0], v1 = p[1], v2 = p[2], v3 = p[3];
      float4 v4 = p[4], v5 = p[5], v6 = p[6], v7 = p[7];
      acc = addf(acc, v0.x); acc = addf(acc, v0.y); acc = addf(acc, v0.z); acc = addf(acc, v0.w);
      acc = addf(acc, v1.x); acc = addf(acc, v1.y); acc = addf(acc, v1.z); acc = addf(acc, v1.w);
      acc = addf(acc, v2.x); acc = addf(acc, v2.y); acc = addf(acc, v2.z); acc = addf(acc, v2.w);
      acc = addf(acc, v3.x); acc = addf(acc, v3.y); acc = addf(acc, v3.z); acc = addf(acc, v3.w);
      acc = addf(acc, v4.x); acc = addf(acc, v4.y); acc = addf(acc, v4.z); acc = addf(acc, v4.w);
      acc = addf(acc, v5.x); acc = addf(acc, v5.y); acc = addf(acc, v5.z); acc = addf(acc, v5.w);
      acc = addf(acc, v6.x); acc = addf(acc, v6.y); acc = addf(acc, v6.z); acc = addf(acc, v6.w);
      acc = addf(acc, v7.x); acc = addf(acc, v7.y); acc = addf(acc, v7.z); acc = addf(acc, v7.w);
    }
  }
  D[blockIdx.x * 256 + x] = acc;
}

// K3: precompute all normals. N[ts][idx], ts = t*4+s, idx in [0, 262144).
__global__ __launch_bounds__(256) void normals_kernel(float* __restrict__ N, NK K) {
  uint32_t g = blockIdx.x * 256 + threadIdx.x;
  uint32_t ts = g >> 18;
  uint32_t idx = g & 262143u;
  N[g] = jax_normal(tf_bits32(K.k[ts][0], K.k[ts][1], idx));
}

// K4: PatchMatch loop — one block per (b, row), lookups only.
__global__ __launch_bounds__(256) void pm_fast(const float* __restrict__ D,
                                               const float* __restrict__ N,
                                               float* __restrict__ out,
                                               uint32_t ki0, uint32_t ki1) {
  const int j = threadIdx.x;
  const int bb = blockIdx.x >> 8;
  const int i = blockIdx.x & 255;
  const float* Db = D + bb * 65536;
  __shared__ float sy[256], sx[256];

  const uint32_t idx_y = (uint32_t)(bb * 131072 + i * 256 + j);
  const uint32_t idx_x = idx_y + 65536u;

  // prefetch all 40 normals into registers (coalesced; constant-indexed)
  float nyv[20], nxv[20];
#pragma unroll
  for (int ts = 0; ts < 20; ++ts) {
    nyv[ts] = N[(size_t)ts * 262144 + idx_y];
    nxv[ts] = N[(size_t)ts * 262144 + idx_x];
  }

  float y = mulf(unitf(tf_bits32(ki0, ki1, idx_y)), 255.0f);
  float x = mulf(unitf(tf_bits32(ki0, ki1, idx_x)), 255.0f);

  auto lookup = [&](float yy, float xx) -> float {
    int iy = (int)rintf(yy);
    int ix = (int)rintf(xx);
    iy = min(max(iy, 0), 255);
    ix = min(max(ix, 0), 255);
    return Db[iy * 256 + ix];
  };

  float curd = lookup(y, x);
#pragma unroll
  for (int t = 0; t < 5; ++t) {
    // propagate +1: shifted[j] = nnf[j-1]
    sy[j] = y; sx[j] = x;
    __syncthreads();
    {
      int jn = (j + 255) & 255;
      float yn = sy[jn], xn = sx[jn];
      float shf = lookup(yn, xn);
      if (shf < curd) { y = yn; x = xn; curd = shf; }
    }
    __syncthreads();
    // propagate -1: shifted[j] = nnf[j+1]
    sy[j] = y; sx[j] = x;
    __syncthreads();
    {
      int jn = (j + 1) & 255;
      float yn = sy[jn], xn = sx[jn];
      float shf = lookup(yn, xn);
      if (shf < curd) { y = yn; x = xn; curd = shf; }
    }
    __syncthreads();
    // random search
    float sigma = 1.0f;
#pragma unroll
    for (int s = 0; s < 4; ++s) {
      float ry = fminf(fmaxf(addf(y, mulf(nyv[t * 4 + s], sigma)), 0.0f), 255.0f);
      float rx = fminf(fmaxf(addf(x, mulf(nxv[t * 4 + s], sigma)), 0.0f), 255.0f);
      float rd = lookup(ry, rx);
      if (rd < curd) { y = ry; x = rx; curd = rd; }
      sigma *= 0.5f;
    }
  }
  out[idx_y] = y;
  out[idx_x] = x;
}

// ========================================================================
// FALLBACK PATH (round-1, proven) — used if ws_size too small
// ========================================================================

__global__ __launch_bounds__(256) void compute_d(const float* __restrict__ S,
                                                 const float* __restrict__ T,
                                                 float* __restrict__ D) {
  const int x = threadIdx.x;
  const int y = blockIdx.x & 255;
  const int b = blockIdx.x >> 8;
  const int chs = 65536;
  const float* Sb = S + (size_t)b * 32 * chs;
  const float* Tb = T + (size_t)b * 32 * chs;
  float acc = 0.0f;
  for (int py = 0; py < 3; ++py) {
    int yy = y + py - 1;
    if (yy < 0 || yy > 255) continue;
    for (int px = 0; px < 3; ++px) {
      int xx = x + px - 1;
      if (xx < 0 || xx > 255) continue;
      int off = yy * 256 + xx;
      for (int c = 0; c < 32; ++c) {
        float d = subf(Sb[c * chs + off], Tb[c * chs + off]);
        acc = addf(acc, mulf(d, d));
      }
    }
  }
  D[b * chs + y * 256 + x] = acc;
}

__global__ __launch_bounds__(256) void pm_kernel(const float* __restrict__ D,
                                                 float* __restrict__ out,
                                                 PMKeys K) {
  const int j = threadIdx.x;
  const int bb = blockIdx.x >> 8;
  const int i = blockIdx.x & 255;
  const float* Db = D + bb * 65536;
  __shared__ float sy[256], sx[256];

  const uint32_t idx_y = (uint32_t)(bb * 131072 + i * 256 + j);
  const uint32_t idx_x = idx_y + 65536u;

  float y = mulf(unitf(tf_bits32(K.ki0, K.ki1, idx_y)), 255.0f);
  float x = mulf(unitf(tf_bits32(K.ki0, K.ki1, idx_x)), 255.0f);

  auto lookup = [&](float yy, float xx) -> float {
    int iy = (int)rintf(yy);
    int ix = (int)rintf(xx);
    iy = min(max(iy, 0), 255);
    ix = min(max(ix, 0), 255);
    return Db[iy * 256 + ix];
  };

  for (int t = 0; t < 5; ++t) {
    sy[j] = y; sx[j] = x;
    __syncthreads();
    {
      int jn = (j + 255) & 255;
      float yn = sy[jn], xn = sx[jn];
      float cur = lookup(y, x);
      float shf = lookup(yn, xn);
      if (shf < cur) { y = yn; x = xn; }
    }
    __syncthreads();
    sy[j] = y; sx[j] = x;
    __syncthreads();
    {
      int jn = (j + 1) & 255;
      float yn = sy[jn], xn = sx[jn];
      float cur = lookup(y, x);
      float shf = lookup(yn, xn);
      if (shf < cur) { y = yn; x = xn; }
    }
    __syncthreads();
    float cur = lookup(y, x);
    float sigma = 1.0f;
    for (int s = 0; s < 4; ++s) {
      uint32_t kk0 = K.sk[t][s][0], kk1 = K.sk[t][s][1];
      float ny = jax_normal(tf_bits32(kk0, kk1, idx_y));
      float nx = jax_normal(tf_bits32(kk0, kk1, idx_x));
      float ry = fminf(fmaxf(addf(y, mulf(ny, sigma)), 0.0f), 255.0f);
      float rx = fminf(fmaxf(addf(x, mulf(nx, sigma)), 0.0f), 255.0f);
      float rd = lookup(ry, rx);
      if (rd < cur) { y = ry; x = rx; cur = rd; }
      sigma *= 0.5f;
    }
  }
  out[idx_y] = y;
  out[idx_x] = x;
}

// ---------- host-side threefry ----------
static void h_tf(uint32_t k0, uint32_t k1, uint32_t x0, uint32_t x1,
                 uint32_t& o0, uint32_t& o1) {
  uint32_t ks2 = k0 ^ k1 ^ 0x1BD11BDAu;
  x0 += k0; x1 += k1;
#define HR(d) { x0 += x1; x1 = (x1 << (d)) | (x1 >> (32 - (d))); x1 ^= x0; }
  HR(13) HR(15) HR(26) HR(6)
  x0 += k1; x1 += ks2 + 1u;
  HR(17) HR(29) HR(16) HR(24)
  x0 += ks2; x1 += k0 + 2u;
  HR(13) HR(15) HR(26) HR(6)
  x0 += k0; x1 += k1 + 3u;
  HR(17) HR(29) HR(16) HR(24)
  x0 += k1; x1 += ks2 + 4u;
  HR(13) HR(15) HR(26) HR(6)
  x0 += ks2; x1 += k0 + 5u;
#undef HR
  o0 = x0; o1 = x1;
}

extern "C" void kernel_launch(void* const* d_in, const int* in_sizes, int n_in,
                              void* d_out, int out_size, void* d_ws, size_t ws_size,
                              hipStream_t stream) {
  const float* S = (const float*)d_in[0];
  const float* T = (const float*)d_in[1];
  float* out = (float*)d_out;

  PMKeys K;
  uint32_t kl0, kl1;
  h_tf(0u, 1u, 0u, 0u, K.ki0, K.ki1);
  h_tf(0u, 1u, 0u, 1u, kl0, kl1);
  for (uint32_t t = 0; t < 5; ++t) {
    uint32_t c0, c1;
    h_tf(kl0, kl1, 0u, t, c0, c1);
    for (int s = 0; s < 4; ++s) {
      uint32_t n0, n1, s0, s1;
      h_tf(c0, c1, 0u, 0u, n0, n1);
      h_tf(c0, c1, 0u, 1u, s0, s1);
      K.sk[t][s][0] = s0; K.sk[t][s][1] = s1;
      c0 = n0; c1 = n1;
    }
  }

  const size_t D_BYTES = 2ull * 65536 * 4;              // 512 KB
  const size_t QN_BYTES = 20ull * 262144 * 4;           // 20 MB (N; Q=16 MB aliases)
  const size_t NEED = D_BYTES + QN_BYTES;

  if (ws_size >= NEED) {
    float* Dd = (float*)d_ws;
    float* QN = (float*)((char*)d_ws + D_BYTES);
    NK nk;
    for (int t = 0; t < 5; ++t)
      for (int s = 0; s < 4; ++s) {
        nk.k[t * 4 + s][0] = K.sk[t][s][0];
        nk.k[t * 4 + s][1] = K.sk[t][s][1];
      }
    hipLaunchKernelGGL(qdiff_kernel, dim3(2048), dim3(256), 0, stream, S, T, QN);
    hipLaunchKernelGGL(dsum_kernel, dim3(512), dim3(256), 0, stream, QN, Dd);
    hipLaunchKernelGGL(normals_kernel, dim3(20480), dim3(256), 0, stream, QN, nk);
    hipLaunchKernelGGL(pm_fast, dim3(512), dim3(256), 0, stream, Dd, QN, out, K.ki0, K.ki1);
  } else {
    float* Dd = (float*)d_ws;
    hipLaunchKernelGGL(compute_d, dim3(512), dim3(256), 0, stream, S, T, Dd);
    hipLaunchKernelGGL(pm_kernel, dim3(512), dim3(256), 0, stream, Dd, out, K);
  }
}